// Round 11
// baseline (100.145 us; speedup 1.0000x reference)
//
#include <hip/hip_runtime.h>
#include <hip/hip_fp16.h>

#define HW 512
#define IMGPIX (HW * HW)
#define NSEG 254
#define NIMG 48
#define SLICE 521  // per-slot float2 LDS stride (512 data + skew)

__device__ __forceinline__ int h2_as_int(__half2 h) {
    int r; __builtin_memcpy(&r, &h, 4); return r;
}
__device__ __forceinline__ __half2 int_as_h2(int v) {
    __half2 h; __builtin_memcpy(&h, &v, 4); return h;
}
// Blocked spectrum layout: G[t][ky][j] (ints = half2), t=x>>2, j=x&3.
__device__ __forceinline__ int gidx(int r, int c) {
    return (r >> 2) * 2048 + c * 4 + (r & 3);
}

// ---------------- 8-point DFT in registers (DIF, natural-order outputs) ----
__device__ __forceinline__ void dft8(float xr[8], float xi[8]) {
    const float C = 0.70710678118654752440f;
    float b0r = xr[0] + xr[4], b0i = xi[0] + xi[4];
    float b1r = xr[1] + xr[5], b1i = xi[1] + xi[5];
    float b2r = xr[2] + xr[6], b2i = xi[2] + xi[6];
    float b3r = xr[3] + xr[7], b3i = xi[3] + xi[7];
    float d4r = xr[0] - xr[4], d4i = xi[0] - xi[4];
    float d5r = xr[1] - xr[5], d5i = xi[1] - xi[5];
    float d6r = xr[2] - xr[6], d6i = xi[2] - xi[6];
    float d7r = xr[3] - xr[7], d7i = xi[3] - xi[7];
    float b4r = d4r, b4i = d4i;
    float b5r = C * (d5r + d5i), b5i = C * (d5i - d5r);   // * W8^1
    float b6r = d6i, b6i = -d6r;                          // * -i
    float b7r = C * (d7i - d7r), b7i = -C * (d7r + d7i);  // * W8^3
    float c0r = b0r + b2r, c0i = b0i + b2i;
    float c1r = b1r + b3r, c1i = b1i + b3i;
    float e2r = b0r - b2r, e2i = b0i - b2i;
    float e3r = b1r - b3r, e3i = b1i - b3i;
    float c3r = e3i, c3i = -e3r;                          // * -i
    float c4r = b4r + b6r, c4i = b4i + b6i;
    float c5r = b5r + b7r, c5i = b5i + b7i;
    float e6r = b4r - b6r, e6i = b4i - b6i;
    float e7r = b5r - b7r, e7i = b5i - b7i;
    float c7r = e7i, c7i = -e7r;                          // * -i
    xr[0] = c0r + c1r; xi[0] = c0i + c1i;
    xr[4] = c0r - c1r; xi[4] = c0i - c1i;
    xr[2] = e2r + c3r; xi[2] = e2i + c3i;
    xr[6] = e2r - c3r; xi[6] = e2i - c3i;
    xr[1] = c4r + c5r; xi[1] = c4i + c5i;
    xr[5] = c4r - c5r; xi[5] = c4i - c5i;
    xr[3] = e6r + c7r; xi[3] = e6i + c7i;
    xr[7] = e6r - c7r; xi[7] = e6i - c7i;
}

__device__ __forceinline__ void tw_apply(float xr[8], float xi[8], float ang) {
    float s, c;
    sincosf(ang, &s, &c);
    float pr = c, pi = s;
#pragma unroll
    for (int k = 1; k < 8; ++k) {
        float tr = xr[k] * pr - xi[k] * pi;
        float ti = xr[k] * pi + xi[k] * pr;
        xr[k] = tr; xi[k] = ti;
        if (k < 7) { float nr = pr * c - pi * s; pi = pr * s + pi * c; pr = nr; }
    }
}

// Per-wave 512-pt FFT. In: slot j holds point n = j*64 + l (natural order).
// Out: lane (hi=l>>3, lo=l&7), slot j3 holds X[hi + 8*lo + 64*j3]; writing
// to ex[hi + (lo<<3) + (j3<<6)] lands X[k] at ex[k]. ex: wave-private
// float2 region. XOR swizzles keep every b64 exchange at the 4-way floor
// (wave64 b64 = 512B = 4 LDS cycles minimum — structural, not fixable).
// No block barriers; same-wave LDS ordering via s_waitcnt only.
__device__ __forceinline__ void wave_fft512(float xr[8], float xi[8],
                                            float2* ex, int l) {
    const float TWO_PI = 6.28318530717958647692f;
    dft8(xr, xi);
    tw_apply(xr, xi, -TWO_PI * (float)l * (1.0f / 512.0f));
#pragma unroll
    for (int k1 = 0; k1 < 8; ++k1)
        ex[k1 * 64 + (l ^ (k1 << 3))] = make_float2(xr[k1], xi[k1]);
    asm volatile("s_waitcnt lgkmcnt(0)" ::: "memory");
    int hi = l >> 3, lo = l & 7;
#pragma unroll
    for (int m1 = 0; m1 < 8; ++m1) {
        float2 v = ex[hi * 64 + ((m1 ^ hi) << 3) + lo];
        xr[m1] = v.x; xi[m1] = v.y;
    }
    dft8(xr, xi);
    tw_apply(xr, xi, -TWO_PI * (float)lo * (1.0f / 64.0f));
#pragma unroll
    for (int j2 = 0; j2 < 8; ++j2)
        ex[hi * 64 + ((j2 ^ hi) << 3) + (lo ^ hi)] = make_float2(xr[j2], xi[j2]);
    asm volatile("s_waitcnt lgkmcnt(0)" ::: "memory");
#pragma unroll
    for (int m2 = 0; m2 < 8; ++m2) {
        float2 v = ex[hi * 64 + ((lo ^ hi) << 3) + (m2 ^ hi)];
        xr[m2] = v.x; xi[m2] = v.y;
    }
    dft8(xr, xi);
}

// Pass 1: row FFT (re=input, im=target packing), one row per wave. Results
// converted to fp16, emitted in the BLOCKED layout G[t][ky][j] via LDS
// restage: block writes 512 contiguous int4 (8KB) — fully coalesced.
// Near input-read floor (~5.9 TB/s effective incl. L3) — leave alone.
__global__ __launch_bounds__(256) void fft_rows_kernel(
    const float* __restrict__ input, const float* __restrict__ target,
    int* __restrict__ G, int img_offset) {
    __shared__ float2 ex[4 * SLICE];
    int tid = threadIdx.x, w = tid >> 6, l = tid & 63;
    int t = blockIdx.x;
    int x = t * 4 + w;
    int li = blockIdx.y;
    const float* ib = input + (size_t)(img_offset + li) * IMGPIX + (size_t)x * HW;
    const float* tb = target + (size_t)(img_offset + li) * IMGPIX + (size_t)x * HW;
    float xr[8], xi[8];
#pragma unroll
    for (int j = 0; j < 8; ++j) {
        xr[j] = ib[j * 64 + l];
        xi[j] = tb[j * 64 + l];
    }
    wave_fft512(xr, xi, ex + w * SLICE, l);
    // fp16 into wave-private int slice (aliases this wave's dead scratch).
    int* isl = (int*)(ex + (size_t)w * SLICE);
    int hi = l >> 3, lo = l & 7;
#pragma unroll
    for (int j3 = 0; j3 < 8; ++j3)
        isl[hi + (lo << 3) + (j3 << 6)] =
            h2_as_int(__float22half2_rn(make_float2(xr[j3], xi[j3])));
    __syncthreads();
    int* i0 = (int*)ex;
    const int SL2 = SLICE * 2;  // int stride between slices
    int* Gt = G + (size_t)li * IMGPIX + t * 2048;
#pragma unroll
    for (int it = 0; it < 2; ++it) {
        int ky = it * 256 + tid;
        int4 o;
        o.x = i0[0 * SL2 + ky];
        o.y = i0[1 * SL2 + ky];
        o.z = i0[2 * SL2 + ky];
        o.w = i0[3 * SL2 + ky];
        *(int4*)(Gt + ky * 4) = o;
    }
}

// Pass 2: x-FFT of 4 ky-columns per block (one per wave, 256 threads),
// in place on the blocked layout. 16.7KB LDS -> 8 blocks/CU (32-wave cap)
// — 2x the occupancy of the 8-col variant (round 10: 50% occ, 3.4 TB/s,
// latency-bound). Staging chunks are 64B contiguous per (t, ky-group).
// DO NOT add gather/map code here: every fused variant (rounds 4-8) made
// hipcc starve this kernel to 32-36 VGPR (needs ~52) -> 3-6x slower.
__global__ __launch_bounds__(256) void fft_cols_kernel(int* __restrict__ G) {
    __shared__ float2 tile[4 * SLICE];
    int tid = threadIdx.x, w = tid >> 6, l = tid & 63;
    int ky0 = blockIdx.x * 4;
    int* Gi = G + (size_t)blockIdx.y * IMGPIX;
#pragma unroll
    for (int it = 0; it < 2; ++it) {
        int m = it * 256 + tid;
        int t = m >> 2, s = m & 3;
        int4 v = *(const int4*)(Gi + t * 2048 + (ky0 + s) * 4);
        float2* dst = tile + s * SLICE + 4 * t;
        dst[0] = __half22float2(int_as_h2(v.x));
        dst[1] = __half22float2(int_as_h2(v.y));
        dst[2] = __half22float2(int_as_h2(v.z));
        dst[3] = __half22float2(int_as_h2(v.w));
    }
    __syncthreads();
    float xr[8], xi[8];
#pragma unroll
    for (int j = 0; j < 8; ++j) {
        float2 v = tile[w * SLICE + j * 64 + l];
        xr[j] = v.x; xi[j] = v.y;
    }
    wave_fft512(xr, xi, tile + w * SLICE, l);  // wave-private slice scratch
    int hi = l >> 3, lo = l & 7;
#pragma unroll
    for (int j3 = 0; j3 < 8; ++j3)
        tile[w * SLICE + hi + (lo << 3) + (j3 << 6)] = make_float2(xr[j3], xi[j3]);
    __syncthreads();
#pragma unroll
    for (int it = 0; it < 2; ++it) {
        int m = it * 256 + tid;
        int t = m >> 2, s = m & 3;
        const float2* src = tile + s * SLICE + 4 * t;
        int4 o;
        o.x = h2_as_int(__float22half2_rn(src[0]));
        o.y = h2_as_int(__float22half2_rn(src[1]));
        o.z = h2_as_int(__float22half2_rn(src[2]));
        o.w = h2_as_int(__float22half2_rn(src[3]));
        *(int4*)(Gi + t * 2048 + (ky0 + s) * 4) = o;
    }
}

// Segment boundary detection: segs is sorted ascending, all segments non-empty.
__global__ void seg_bounds_kernel(const int* __restrict__ segs,
                                  int* __restrict__ seg_start, int P) {
    int p = blockIdx.x * 256 + threadIdx.x;
    if (p >= P) return;
    if (p == 0) {
        seg_start[0] = 0;
        seg_start[NSEG] = P;
    } else if (segs[p] != segs[p - 1]) {
        seg_start[segs[p]] = p;
    }
}

// One wave per (local img, segment). Packed-FFT split via conj symmetry:
// u=F[r,c], v=F[-r,-c]; a=(u.x+v.x, u.y-v.y), b=(u.y+v.y, v.x-u.x).
// CANONICAL-HALF: the point set is centrally symmetric and a mirror entry's
// contribution is the conjugate (same Re-cross, e1, e2), so summing only
// entries with c<256 (or c==256 && r<256) scales (cross,e1,e2) uniformly
// by 1/2 — which cancels in |cross|/sqrt(e1*e2). Total cross is real, so
// only Re is accumulated. Halves the scattered loads.
__global__ __launch_bounds__(64) void gather_kernel(
    const int* __restrict__ G, const int* __restrict__ rows,
    const int* __restrict__ cols, const int* __restrict__ seg_start,
    float4* __restrict__ acc, int img_offset) {
    int li = blockIdx.x;
    int s = blockIdx.y;
    int p0 = seg_start[s], p1 = seg_start[s + 1];
    const int* A = G + (size_t)li * IMGPIX;
    float cr = 0.f, e1 = 0.f, e2 = 0.f;
    for (int p = p0 + threadIdx.x; p < p1; p += 64) {
        int r = rows[p], c = cols[p];
        if (c > 256 || (c == 256 && r >= 256)) continue;
        float2 u = __half22float2(int_as_h2(A[gidx(r, c)]));
        float2 v = __half22float2(int_as_h2(A[gidx(HW - r, HW - c)]));
        float ar = u.x + v.x, ai = u.y - v.y;
        float br = u.y + v.y, bi = v.x - u.x;
        cr += ar * br + ai * bi;
        e1 += ar * ar + ai * ai;
        e2 += br * br + bi * bi;
    }
#pragma unroll
    for (int off = 32; off >= 1; off >>= 1) {
        cr += __shfl_down(cr, off, 64);
        e1 += __shfl_down(e1, off, 64);
        e2 += __shfl_down(e2, off, 64);
    }
    if (threadIdx.x == 0)
        acc[(size_t)s * NIMG + (img_offset + li)] = make_float4(cr, 0.f, e1, e2);
}

__global__ __launch_bounds__(64) void final_kernel(
    const float4* __restrict__ acc, const float* __restrict__ weight,
    const float* __restrict__ bias, float* __restrict__ out) {
    int img = blockIdx.x;
    int t = threadIdx.x;
    float sum = 0.f;
    for (int s = t; s < NSEG; s += 64) {
        float4 v = acc[(size_t)s * NIMG + img];
        sum += weight[s + 1] * (fabsf(v.x) * rsqrtf(v.z * v.w));
    }
#pragma unroll
    for (int off = 32; off >= 1; off >>= 1) sum += __shfl_down(sum, off, 64);
    if (t == 0) out[img] = sum + weight[0] + bias[0];
}

extern "C" void kernel_launch(void* const* d_in, const int* in_sizes, int n_in,
                              void* d_out, int out_size, void* d_ws, size_t ws_size,
                              hipStream_t stream) {
    const float* input  = (const float*)d_in[0];
    const float* target = (const float*)d_in[1];
    const int* rows     = (const int*)d_in[2];
    const int* cols     = (const int*)d_in[3];
    const int* segs     = (const int*)d_in[4];
    const float* weight = (const float*)d_in[5];
    const float* bias   = (const float*)d_in[6];
    float* out = (float*)d_out;
    int P = in_sizes[2];

    char* ws = (char*)d_ws;
    float4* acc = (float4*)ws;                               // NSEG*NIMG float4
    size_t accBytes = (size_t)NSEG * NIMG * sizeof(float4);  // 195072 B
    int* seg_start = (int*)(ws + accBytes);                  // 256 ints
    size_t off = accBytes + 256 * sizeof(int);
    off = (off + 255) & ~(size_t)255;
    size_t remain = (ws_size > off) ? (ws_size - off) : 0;
    size_t perImg = (size_t)IMGPIX * sizeof(int);            // 1 MB per image
    const int chs[10] = {48, 24, 16, 12, 8, 6, 4, 3, 2, 1};
    int CH = 1;
    for (int i = 0; i < 10; ++i)
        if ((size_t)chs[i] * perImg <= remain) { CH = chs[i]; break; }
    int* G = (int*)(ws + off);

    seg_bounds_kernel<<<(P + 255) / 256, 256, 0, stream>>>(segs, seg_start, P);

    for (int k = 0; k < NIMG; k += CH) {
        dim3 g1(HW / 4, CH);
        fft_rows_kernel<<<g1, 256, 0, stream>>>(input, target, G, k);
        dim3 g2(HW / 4, CH);
        fft_cols_kernel<<<g2, 256, 0, stream>>>(G);
        dim3 g3(CH, NSEG);
        gather_kernel<<<g3, 64, 0, stream>>>(G, rows, cols, seg_start, acc, k);
    }
    final_kernel<<<NIMG, 64, 0, stream>>>(acc, weight, bias, out);
}

// Round 12
// 93.838 us; speedup vs baseline: 1.0672x; 1.0672x over previous
//
#include <hip/hip_runtime.h>
#include <hip/hip_fp16.h>

#define HW 512
#define IMGPIX (HW * HW)
#define NSEG 254
#define NIMG 48
#define SLICE 521  // per-slot float2 LDS stride (512 data + skew)

__device__ __forceinline__ int h2_as_int(__half2 h) {
    int r; __builtin_memcpy(&r, &h, 4); return r;
}
__device__ __forceinline__ __half2 int_as_h2(int v) {
    __half2 h; __builtin_memcpy(&h, &v, 4); return h;
}
// Blocked spectrum layout: G[t][ky][j] (ints = half2), t=x>>2, j=x&3.
__device__ __forceinline__ int gidx(int r, int c) {
    return (r >> 2) * 2048 + c * 4 + (r & 3);
}

// ---------------- 8-point DFT in registers (DIF, natural-order outputs) ----
__device__ __forceinline__ void dft8(float xr[8], float xi[8]) {
    const float C = 0.70710678118654752440f;
    float b0r = xr[0] + xr[4], b0i = xi[0] + xi[4];
    float b1r = xr[1] + xr[5], b1i = xi[1] + xi[5];
    float b2r = xr[2] + xr[6], b2i = xi[2] + xi[6];
    float b3r = xr[3] + xr[7], b3i = xi[3] + xi[7];
    float d4r = xr[0] - xr[4], d4i = xi[0] - xi[4];
    float d5r = xr[1] - xr[5], d5i = xi[1] - xi[5];
    float d6r = xr[2] - xr[6], d6i = xi[2] - xi[6];
    float d7r = xr[3] - xr[7], d7i = xi[3] - xi[7];
    float b4r = d4r, b4i = d4i;
    float b5r = C * (d5r + d5i), b5i = C * (d5i - d5r);   // * W8^1
    float b6r = d6i, b6i = -d6r;                          // * -i
    float b7r = C * (d7i - d7r), b7i = -C * (d7r + d7i);  // * W8^3
    float c0r = b0r + b2r, c0i = b0i + b2i;
    float c1r = b1r + b3r, c1i = b1i + b3i;
    float e2r = b0r - b2r, e2i = b0i - b2i;
    float e3r = b1r - b3r, e3i = b1i - b3i;
    float c3r = e3i, c3i = -e3r;                          // * -i
    float c4r = b4r + b6r, c4i = b4i + b6i;
    float c5r = b5r + b7r, c5i = b5i + b7i;
    float e6r = b4r - b6r, e6i = b4i - b6i;
    float e7r = b5r - b7r, e7i = b5i - b7i;
    float c7r = e7i, c7i = -e7r;                          // * -i
    xr[0] = c0r + c1r; xi[0] = c0i + c1i;
    xr[4] = c0r - c1r; xi[4] = c0i - c1i;
    xr[2] = e2r + c3r; xi[2] = e2i + c3i;
    xr[6] = e2r - c3r; xi[6] = e2i - c3i;
    xr[1] = c4r + c5r; xi[1] = c4i + c5i;
    xr[5] = c4r - c5r; xi[5] = c4i - c5i;
    xr[3] = e6r + c7r; xi[3] = e6i + c7i;
    xr[7] = e6r - c7r; xi[7] = e6i - c7i;
}

__device__ __forceinline__ void tw_apply(float xr[8], float xi[8], float ang) {
    float s, c;
    sincosf(ang, &s, &c);
    float pr = c, pi = s;
#pragma unroll
    for (int k = 1; k < 8; ++k) {
        float tr = xr[k] * pr - xi[k] * pi;
        float ti = xr[k] * pi + xi[k] * pr;
        xr[k] = tr; xi[k] = ti;
        if (k < 7) { float nr = pr * c - pi * s; pi = pr * s + pi * c; pr = nr; }
    }
}

// Per-wave 512-pt FFT. In: slot j holds point n = j*64 + l (natural order).
// Out: lane (hi=l>>3, lo=l&7), slot j3 holds X[hi + 8*lo + 64*j3]; writing
// to ex[hi + (lo<<3) + (j3<<6)] lands X[k] at ex[k]. ex: wave-private
// float2 region. XOR swizzles keep every b64 exchange at the 4-way floor.
// No block barriers; same-wave LDS ordering via s_waitcnt only.
__device__ __forceinline__ void wave_fft512(float xr[8], float xi[8],
                                            float2* ex, int l) {
    const float TWO_PI = 6.28318530717958647692f;
    dft8(xr, xi);
    tw_apply(xr, xi, -TWO_PI * (float)l * (1.0f / 512.0f));
#pragma unroll
    for (int k1 = 0; k1 < 8; ++k1)
        ex[k1 * 64 + (l ^ (k1 << 3))] = make_float2(xr[k1], xi[k1]);
    asm volatile("s_waitcnt lgkmcnt(0)" ::: "memory");
    int hi = l >> 3, lo = l & 7;
#pragma unroll
    for (int m1 = 0; m1 < 8; ++m1) {
        float2 v = ex[hi * 64 + ((m1 ^ hi) << 3) + lo];
        xr[m1] = v.x; xi[m1] = v.y;
    }
    dft8(xr, xi);
    tw_apply(xr, xi, -TWO_PI * (float)lo * (1.0f / 64.0f));
#pragma unroll
    for (int j2 = 0; j2 < 8; ++j2)
        ex[hi * 64 + ((j2 ^ hi) << 3) + (lo ^ hi)] = make_float2(xr[j2], xi[j2]);
    asm volatile("s_waitcnt lgkmcnt(0)" ::: "memory");
#pragma unroll
    for (int m2 = 0; m2 < 8; ++m2) {
        float2 v = ex[hi * 64 + ((lo ^ hi) << 3) + (m2 ^ hi)];
        xr[m2] = v.x; xi[m2] = v.y;
    }
    dft8(xr, xi);
}

// Pass 1: row FFT (re=input, im=target packing), one row per wave. Results
// converted to fp16, emitted in the BLOCKED layout G[t][ky][j] via LDS
// restage: block writes 512 contiguous int4 (8KB) — fully coalesced.
__global__ __launch_bounds__(256) void fft_rows_kernel(
    const float* __restrict__ input, const float* __restrict__ target,
    int* __restrict__ G, int img_offset) {
    __shared__ float2 ex[4 * SLICE];
    int tid = threadIdx.x, w = tid >> 6, l = tid & 63;
    int t = blockIdx.x;
    int x = t * 4 + w;
    int li = blockIdx.y;
    const float* ib = input + (size_t)(img_offset + li) * IMGPIX + (size_t)x * HW;
    const float* tb = target + (size_t)(img_offset + li) * IMGPIX + (size_t)x * HW;
    float xr[8], xi[8];
#pragma unroll
    for (int j = 0; j < 8; ++j) {
        xr[j] = ib[j * 64 + l];
        xi[j] = tb[j * 64 + l];
    }
    wave_fft512(xr, xi, ex + w * SLICE, l);
    // fp16 into wave-private int slice (aliases this wave's dead scratch).
    int* isl = (int*)(ex + (size_t)w * SLICE);
    int hi = l >> 3, lo = l & 7;
#pragma unroll
    for (int j3 = 0; j3 < 8; ++j3)
        isl[hi + (lo << 3) + (j3 << 6)] =
            h2_as_int(__float22half2_rn(make_float2(xr[j3], xi[j3])));
    __syncthreads();
    int* i0 = (int*)ex;
    const int SL2 = SLICE * 2;  // int stride between slices
    int* Gt = G + (size_t)li * IMGPIX + t * 2048;
#pragma unroll
    for (int it = 0; it < 2; ++it) {
        int ky = it * 256 + tid;
        int4 o;
        o.x = i0[0 * SL2 + ky];
        o.y = i0[1 * SL2 + ky];
        o.z = i0[2 * SL2 + ky];
        o.w = i0[3 * SL2 + ky];
        *(int4*)(Gt + ky * 4) = o;
    }
}

// Pass 2: x-FFT of 4 ky-columns per block (one per wave, 256 threads),
// in place on the blocked layout. 16.7KB LDS -> 8 blocks/CU.
// DO NOT add gather/map code here: every fused variant (rounds 4-8) made
// hipcc starve this kernel to 32-36 VGPR (needs ~52) -> 3-6x slower.
__global__ __launch_bounds__(256) void fft_cols_kernel(int* __restrict__ G) {
    __shared__ float2 tile[4 * SLICE];
    int tid = threadIdx.x, w = tid >> 6, l = tid & 63;
    int ky0 = blockIdx.x * 4;
    int* Gi = G + (size_t)blockIdx.y * IMGPIX;
#pragma unroll
    for (int it = 0; it < 2; ++it) {
        int m = it * 256 + tid;
        int t = m >> 2, s = m & 3;
        int4 v = *(const int4*)(Gi + t * 2048 + (ky0 + s) * 4);
        float2* dst = tile + s * SLICE + 4 * t;
        dst[0] = __half22float2(int_as_h2(v.x));
        dst[1] = __half22float2(int_as_h2(v.y));
        dst[2] = __half22float2(int_as_h2(v.z));
        dst[3] = __half22float2(int_as_h2(v.w));
    }
    __syncthreads();
    float xr[8], xi[8];
#pragma unroll
    for (int j = 0; j < 8; ++j) {
        float2 v = tile[w * SLICE + j * 64 + l];
        xr[j] = v.x; xi[j] = v.y;
    }
    wave_fft512(xr, xi, tile + w * SLICE, l);  // wave-private slice scratch
    int hi = l >> 3, lo = l & 7;
#pragma unroll
    for (int j3 = 0; j3 < 8; ++j3)
        tile[w * SLICE + hi + (lo << 3) + (j3 << 6)] = make_float2(xr[j3], xi[j3]);
    __syncthreads();
#pragma unroll
    for (int it = 0; it < 2; ++it) {
        int m = it * 256 + tid;
        int t = m >> 2, s = m & 3;
        const float2* src = tile + s * SLICE + 4 * t;
        int4 o;
        o.x = h2_as_int(__float22half2_rn(src[0]));
        o.y = h2_as_int(__float22half2_rn(src[1]));
        o.z = h2_as_int(__float22half2_rn(src[2]));
        o.w = h2_as_int(__float22half2_rn(src[3]));
        *(int4*)(Gi + t * 2048 + (ky0 + s) * 4) = o;
    }
}

// Segment boundaries + per-point pair indices (both rebuilt every call).
__global__ void seg_bounds_kernel(const int* __restrict__ segs,
                                  int* __restrict__ seg_start, int P) {
    int p = blockIdx.x * 256 + threadIdx.x;
    if (p >= P) return;
    if (p == 0) {
        seg_start[0] = 0;
        seg_start[NSEG] = P;
    } else if (segs[p] != segs[p - 1]) {
        seg_start[segs[p]] = p;
    }
}

// IDX[p] = {gidx(r,c), gidx(-r,-c)}: one 8B contiguous load in the gather
// replaces rows+cols loads and all index math (r,c in [3,509], no wrap).
__global__ void prep_idx_kernel(const int* __restrict__ rows,
                                const int* __restrict__ cols,
                                int2* __restrict__ IDX, int P) {
    int p = blockIdx.x * 256 + threadIdx.x;
    if (p >= P) return;
    int r = rows[p], c = cols[p];
    IDX[p] = make_int2(gidx(r, c), gidx(HW - r, HW - c));
}

// One 256-thread block (4 waves) per (local img, segment). STRAIGHT-LINE
// body (no branches): round 11's canonical-half `continue` collapsed the
// compiler's load pipelining (VGPR 12, 3.4x slower). Full-list sum double
// counts each mirror pair uniformly (mirror contribution is the exact
// conjugate: same Re-cross/e1/e2) — the x2 cancels in |cross|/sqrt(e1*e2),
// and Im(cross) cancels exactly, so 3 accumulators suffice.
__global__ __launch_bounds__(256) void gather_kernel(
    const int* __restrict__ G, const int2* __restrict__ IDX,
    const int* __restrict__ seg_start, float4* __restrict__ acc,
    int img_offset) {
    int li = blockIdx.x;
    int s = blockIdx.y;
    int p0 = seg_start[s], p1 = seg_start[s + 1];
    const int* A = G + (size_t)li * IMGPIX;
    float cr = 0.f, e1 = 0.f, e2 = 0.f;
    for (int p = p0 + threadIdx.x; p < p1; p += 256) {
        int2 ix = IDX[p];
        float2 u = __half22float2(int_as_h2(A[ix.x]));
        float2 v = __half22float2(int_as_h2(A[ix.y]));
        float ar = u.x + v.x, ai = u.y - v.y;
        float br = u.y + v.y, bi = v.x - u.x;
        cr += ar * br + ai * bi;
        e1 += ar * ar + ai * ai;
        e2 += br * br + bi * bi;
    }
#pragma unroll
    for (int off = 32; off >= 1; off >>= 1) {
        cr += __shfl_down(cr, off, 64);
        e1 += __shfl_down(e1, off, 64);
        e2 += __shfl_down(e2, off, 64);
    }
    __shared__ float4 part[4];
    int wid = threadIdx.x >> 6, lane = threadIdx.x & 63;
    if (lane == 0) part[wid] = make_float4(cr, 0.f, e1, e2);
    __syncthreads();
    if (threadIdx.x == 0) {
        float4 t0 = part[0], t1 = part[1], t2 = part[2], t3 = part[3];
        acc[(size_t)s * NIMG + (img_offset + li)] =
            make_float4(t0.x + t1.x + t2.x + t3.x, 0.f,
                        t0.z + t1.z + t2.z + t3.z, t0.w + t1.w + t2.w + t3.w);
    }
}

__global__ __launch_bounds__(64) void final_kernel(
    const float4* __restrict__ acc, const float* __restrict__ weight,
    const float* __restrict__ bias, float* __restrict__ out) {
    int img = blockIdx.x;
    int t = threadIdx.x;
    float sum = 0.f;
    for (int s = t; s < NSEG; s += 64) {
        float4 v = acc[(size_t)s * NIMG + img];
        sum += weight[s + 1] * (fabsf(v.x) * rsqrtf(v.z * v.w));
    }
#pragma unroll
    for (int off = 32; off >= 1; off >>= 1) sum += __shfl_down(sum, off, 64);
    if (t == 0) out[img] = sum + weight[0] + bias[0];
}

extern "C" void kernel_launch(void* const* d_in, const int* in_sizes, int n_in,
                              void* d_out, int out_size, void* d_ws, size_t ws_size,
                              hipStream_t stream) {
    const float* input  = (const float*)d_in[0];
    const float* target = (const float*)d_in[1];
    const int* rows     = (const int*)d_in[2];
    const int* cols     = (const int*)d_in[3];
    const int* segs     = (const int*)d_in[4];
    const float* weight = (const float*)d_in[5];
    const float* bias   = (const float*)d_in[6];
    float* out = (float*)d_out;
    int P = in_sizes[2];

    char* ws = (char*)d_ws;
    float4* acc = (float4*)ws;                               // NSEG*NIMG float4
    size_t accBytes = (size_t)NSEG * NIMG * sizeof(float4);  // 195072 B
    int* seg_start = (int*)(ws + accBytes);                  // 256 ints
    size_t off = accBytes + 256 * sizeof(int);
    off = (off + 255) & ~(size_t)255;
    int2* IDX = (int2*)(ws + off);                           // P int2 ~1.5 MB
    off += (size_t)P * sizeof(int2);
    off = (off + 255) & ~(size_t)255;
    size_t remain = (ws_size > off) ? (ws_size - off) : 0;
    size_t perImg = (size_t)IMGPIX * sizeof(int);            // 1 MB per image
    const int chs[10] = {48, 24, 16, 12, 8, 6, 4, 3, 2, 1};
    int CH = 1;
    for (int i = 0; i < 10; ++i)
        if ((size_t)chs[i] * perImg <= remain) { CH = chs[i]; break; }
    int* G = (int*)(ws + off);

    seg_bounds_kernel<<<(P + 255) / 256, 256, 0, stream>>>(segs, seg_start, P);
    prep_idx_kernel<<<(P + 255) / 256, 256, 0, stream>>>(rows, cols, IDX, P);

    for (int k = 0; k < NIMG; k += CH) {
        dim3 g1(HW / 4, CH);
        fft_rows_kernel<<<g1, 256, 0, stream>>>(input, target, G, k);
        dim3 g2(HW / 4, CH);
        fft_cols_kernel<<<g2, 256, 0, stream>>>(G);
        dim3 g3(CH, NSEG);
        gather_kernel<<<g3, 256, 0, stream>>>(G, IDX, seg_start, acc, k);
    }
    final_kernel<<<NIMG, 64, 0, stream>>>(acc, weight, bias, out);
}

// Round 13
// 84.813 us; speedup vs baseline: 1.1808x; 1.1064x over previous
//
#include <hip/hip_runtime.h>
#include <hip/hip_fp16.h>

#define HW 512
#define IMGPIX (HW * HW)
#define NSEG 254
#define NIMG 48
#define SLICE 521  // per-slot float2 LDS stride (512 data + skew)

__device__ __forceinline__ int h2_as_int(__half2 h) {
    int r; __builtin_memcpy(&r, &h, 4); return r;
}
__device__ __forceinline__ __half2 int_as_h2(int v) {
    __half2 h; __builtin_memcpy(&h, &v, 4); return h;
}
// Blocked spectrum layout: G[t][ky][j] (ints = half2), t=x>>2, j=x&3.
__device__ __forceinline__ int gidx(int r, int c) {
    return (r >> 2) * 2048 + c * 4 + (r & 3);
}

// ---------------- 8-point DFT in registers (DIF, natural-order outputs) ----
__device__ __forceinline__ void dft8(float xr[8], float xi[8]) {
    const float C = 0.70710678118654752440f;
    float b0r = xr[0] + xr[4], b0i = xi[0] + xi[4];
    float b1r = xr[1] + xr[5], b1i = xi[1] + xi[5];
    float b2r = xr[2] + xr[6], b2i = xi[2] + xi[6];
    float b3r = xr[3] + xr[7], b3i = xi[3] + xi[7];
    float d4r = xr[0] - xr[4], d4i = xi[0] - xi[4];
    float d5r = xr[1] - xr[5], d5i = xi[1] - xi[5];
    float d6r = xr[2] - xr[6], d6i = xi[2] - xi[6];
    float d7r = xr[3] - xr[7], d7i = xi[3] - xi[7];
    float b4r = d4r, b4i = d4i;
    float b5r = C * (d5r + d5i), b5i = C * (d5i - d5r);   // * W8^1
    float b6r = d6i, b6i = -d6r;                          // * -i
    float b7r = C * (d7i - d7r), b7i = -C * (d7r + d7i);  // * W8^3
    float c0r = b0r + b2r, c0i = b0i + b2i;
    float c1r = b1r + b3r, c1i = b1i + b3i;
    float e2r = b0r - b2r, e2i = b0i - b2i;
    float e3r = b1r - b3r, e3i = b1i - b3i;
    float c3r = e3i, c3i = -e3r;                          // * -i
    float c4r = b4r + b6r, c4i = b4i + b6i;
    float c5r = b5r + b7r, c5i = b5i + b7i;
    float e6r = b4r - b6r, e6i = b4i - b6i;
    float e7r = b5r - b7r, e7i = b5i - b7i;
    float c7r = e7i, c7i = -e7r;                          // * -i
    xr[0] = c0r + c1r; xi[0] = c0i + c1i;
    xr[4] = c0r - c1r; xi[4] = c0i - c1i;
    xr[2] = e2r + c3r; xi[2] = e2i + c3i;
    xr[6] = e2r - c3r; xi[6] = e2i - c3i;
    xr[1] = c4r + c5r; xi[1] = c4i + c5i;
    xr[5] = c4r - c5r; xi[5] = c4i - c5i;
    xr[3] = e6r + c7r; xi[3] = e6i + c7i;
    xr[7] = e6r - c7r; xi[7] = e6i - c7i;
}

// Multiply slot k by w^k, w = e^{i*ang}. NATIVE __sinf/__cosf (v_sin_f32 /
// v_cos_f32, 2 inst each) — libm sincosf is ~40 VALU ops of range
// reduction and was a large slice of both FFT kernels' VALUBusy.
__device__ __forceinline__ void tw_apply(float xr[8], float xi[8], float ang) {
    float s = __sinf(ang), c = __cosf(ang);
    float pr = c, pi = s;
#pragma unroll
    for (int k = 1; k < 8; ++k) {
        float tr = xr[k] * pr - xi[k] * pi;
        float ti = xr[k] * pi + xi[k] * pr;
        xr[k] = tr; xi[k] = ti;
        if (k < 7) { float nr = pr * c - pi * s; pi = pr * s + pi * c; pr = nr; }
    }
}

// Per-wave 512-pt FFT. In: slot j holds point n = j*64 + l (natural order).
// Out: lane (hi=l>>3, lo=l&7), slot j3 holds X[hi + 8*lo + 64*j3]; writing
// to ex[hi + (lo<<3) + (j3<<6)] lands X[k] at ex[k]. ex: wave-private
// float2 region. XOR swizzles keep every b64 exchange at the 4-way floor.
// No block barriers; same-wave LDS ordering via s_waitcnt only.
__device__ __forceinline__ void wave_fft512(float xr[8], float xi[8],
                                            float2* ex, int l) {
    const float TWO_PI = 6.28318530717958647692f;
    dft8(xr, xi);
    tw_apply(xr, xi, -TWO_PI * (float)l * (1.0f / 512.0f));
#pragma unroll
    for (int k1 = 0; k1 < 8; ++k1)
        ex[k1 * 64 + (l ^ (k1 << 3))] = make_float2(xr[k1], xi[k1]);
    asm volatile("s_waitcnt lgkmcnt(0)" ::: "memory");
    int hi = l >> 3, lo = l & 7;
#pragma unroll
    for (int m1 = 0; m1 < 8; ++m1) {
        float2 v = ex[hi * 64 + ((m1 ^ hi) << 3) + lo];
        xr[m1] = v.x; xi[m1] = v.y;
    }
    dft8(xr, xi);
    tw_apply(xr, xi, -TWO_PI * (float)lo * (1.0f / 64.0f));
#pragma unroll
    for (int j2 = 0; j2 < 8; ++j2)
        ex[hi * 64 + ((j2 ^ hi) << 3) + (lo ^ hi)] = make_float2(xr[j2], xi[j2]);
    asm volatile("s_waitcnt lgkmcnt(0)" ::: "memory");
#pragma unroll
    for (int m2 = 0; m2 < 8; ++m2) {
        float2 v = ex[hi * 64 + ((lo ^ hi) << 3) + (m2 ^ hi)];
        xr[m2] = v.x; xi[m2] = v.y;
    }
    dft8(xr, xi);
}

// Pass 1: row FFT (re=input, im=target packing), one row per wave. Results
// converted to fp16, emitted in the BLOCKED layout G[t][ky][j] via LDS
// restage: block writes 512 contiguous int4 (8KB) — fully coalesced.
__global__ __launch_bounds__(256) void fft_rows_kernel(
    const float* __restrict__ input, const float* __restrict__ target,
    int* __restrict__ G, int img_offset) {
    __shared__ float2 ex[4 * SLICE];
    int tid = threadIdx.x, w = tid >> 6, l = tid & 63;
    int t = blockIdx.x;
    int x = t * 4 + w;
    int li = blockIdx.y;
    const float* ib = input + (size_t)(img_offset + li) * IMGPIX + (size_t)x * HW;
    const float* tb = target + (size_t)(img_offset + li) * IMGPIX + (size_t)x * HW;
    float xr[8], xi[8];
#pragma unroll
    for (int j = 0; j < 8; ++j) {
        xr[j] = ib[j * 64 + l];
        xi[j] = tb[j * 64 + l];
    }
    wave_fft512(xr, xi, ex + w * SLICE, l);
    // fp16 into wave-private int slice (aliases this wave's dead scratch).
    int* isl = (int*)(ex + (size_t)w * SLICE);
    int hi = l >> 3, lo = l & 7;
#pragma unroll
    for (int j3 = 0; j3 < 8; ++j3)
        isl[hi + (lo << 3) + (j3 << 6)] =
            h2_as_int(__float22half2_rn(make_float2(xr[j3], xi[j3])));
    __syncthreads();
    int* i0 = (int*)ex;
    const int SL2 = SLICE * 2;  // int stride between slices
    int* Gt = G + (size_t)li * IMGPIX + t * 2048;
#pragma unroll
    for (int it = 0; it < 2; ++it) {
        int ky = it * 256 + tid;
        int4 o;
        o.x = i0[0 * SL2 + ky];
        o.y = i0[1 * SL2 + ky];
        o.z = i0[2 * SL2 + ky];
        o.w = i0[3 * SL2 + ky];
        *(int4*)(Gt + ky * 4) = o;
    }
}

// Pass 2: x-FFT of 4 ky-columns per block (one per wave, 256 threads),
// in place on the blocked layout. 16.7KB LDS -> 8 blocks/CU.
// DO NOT add gather/map code here: every fused variant (rounds 4-8) made
// hipcc starve this kernel to 32-36 VGPR (needs ~52) -> 3-6x slower.
__global__ __launch_bounds__(256) void fft_cols_kernel(int* __restrict__ G) {
    __shared__ float2 tile[4 * SLICE];
    int tid = threadIdx.x, w = tid >> 6, l = tid & 63;
    int ky0 = blockIdx.x * 4;
    int* Gi = G + (size_t)blockIdx.y * IMGPIX;
#pragma unroll
    for (int it = 0; it < 2; ++it) {
        int m = it * 256 + tid;
        int t = m >> 2, s = m & 3;
        int4 v = *(const int4*)(Gi + t * 2048 + (ky0 + s) * 4);
        float2* dst = tile + s * SLICE + 4 * t;
        dst[0] = __half22float2(int_as_h2(v.x));
        dst[1] = __half22float2(int_as_h2(v.y));
        dst[2] = __half22float2(int_as_h2(v.z));
        dst[3] = __half22float2(int_as_h2(v.w));
    }
    __syncthreads();
    float xr[8], xi[8];
#pragma unroll
    for (int j = 0; j < 8; ++j) {
        float2 v = tile[w * SLICE + j * 64 + l];
        xr[j] = v.x; xi[j] = v.y;
    }
    wave_fft512(xr, xi, tile + w * SLICE, l);  // wave-private slice scratch
    int hi = l >> 3, lo = l & 7;
#pragma unroll
    for (int j3 = 0; j3 < 8; ++j3)
        tile[w * SLICE + hi + (lo << 3) + (j3 << 6)] = make_float2(xr[j3], xi[j3]);
    __syncthreads();
#pragma unroll
    for (int it = 0; it < 2; ++it) {
        int m = it * 256 + tid;
        int t = m >> 2, s = m & 3;
        const float2* src = tile + s * SLICE + 4 * t;
        int4 o;
        o.x = h2_as_int(__float22half2_rn(src[0]));
        o.y = h2_as_int(__float22half2_rn(src[1]));
        o.z = h2_as_int(__float22half2_rn(src[2]));
        o.w = h2_as_int(__float22half2_rn(src[3]));
        *(int4*)(Gi + t * 2048 + (ky0 + s) * 4) = o;
    }
}

// Prep: segment boundaries (list entries, sorted by seg, 8-aligned ranges)
// + compacted CANONICAL pair-index list. Bresenham emits 8 octant entries
// per step; within each group of 8, the central mirror of position j in
// {0,1,4,5} is {3,2,7,6}[j] — so canonical q maps to list position
// p = 8*(q>>2) + LUT[q&3] with NO data-dependent branch. Mirror entries
// contribute the exact conjugate (same Re-cross/e1/e2), so summing the
// canonical half scales all three sums by 1/2 — cancels in FRC.
__global__ void prep_kernel(const int* __restrict__ rows,
                            const int* __restrict__ cols,
                            const int* __restrict__ segs,
                            int* __restrict__ seg_start,
                            int2* __restrict__ IDXc, int P) {
    int p = blockIdx.x * 256 + threadIdx.x;
    if (p >= P) return;
    if (p == 0) {
        seg_start[0] = 0;
        seg_start[NSEG] = P;
    } else if (segs[p] != segs[p - 1]) {
        seg_start[segs[p]] = p;
    }
    int q = p;  // reuse thread index as canonical index for q < P/2
    if (q < (P >> 1)) {
        const int LUT[4] = {0, 1, 4, 5};
        int src = ((q >> 2) << 3) + LUT[q & 3];
        int r = rows[src], c = cols[src];
        IDXc[q] = make_int2(gidx(r, c), gidx(HW - r, HW - c));
    }
}

// One 256-thread block (4 waves) per (local img, segment), canonical half
// only (q-range = seg range / 2). STRAIGHT-LINE body — round 11 showed a
// data-dependent `continue` kills the compiler's load pipelining.
__global__ __launch_bounds__(256) void gather_kernel(
    const int* __restrict__ G, const int2* __restrict__ IDXc,
    const int* __restrict__ seg_start, float4* __restrict__ acc,
    int img_offset) {
    int li = blockIdx.x;
    int s = blockIdx.y;
    int q0 = seg_start[s] >> 1, q1 = seg_start[s + 1] >> 1;
    const int* A = G + (size_t)li * IMGPIX;
    float cr = 0.f, e1 = 0.f, e2 = 0.f;
    for (int q = q0 + threadIdx.x; q < q1; q += 256) {
        int2 ix = IDXc[q];
        float2 u = __half22float2(int_as_h2(A[ix.x]));
        float2 v = __half22float2(int_as_h2(A[ix.y]));
        float ar = u.x + v.x, ai = u.y - v.y;
        float br = u.y + v.y, bi = v.x - u.x;
        cr += ar * br + ai * bi;
        e1 += ar * ar + ai * ai;
        e2 += br * br + bi * bi;
    }
#pragma unroll
    for (int off = 32; off >= 1; off >>= 1) {
        cr += __shfl_down(cr, off, 64);
        e1 += __shfl_down(e1, off, 64);
        e2 += __shfl_down(e2, off, 64);
    }
    __shared__ float4 part[4];
    int wid = threadIdx.x >> 6, lane = threadIdx.x & 63;
    if (lane == 0) part[wid] = make_float4(cr, 0.f, e1, e2);
    __syncthreads();
    if (threadIdx.x == 0) {
        float4 t0 = part[0], t1 = part[1], t2 = part[2], t3 = part[3];
        acc[(size_t)s * NIMG + (img_offset + li)] =
            make_float4(t0.x + t1.x + t2.x + t3.x, 0.f,
                        t0.z + t1.z + t2.z + t3.z, t0.w + t1.w + t2.w + t3.w);
    }
}

__global__ __launch_bounds__(64) void final_kernel(
    const float4* __restrict__ acc, const float* __restrict__ weight,
    const float* __restrict__ bias, float* __restrict__ out) {
    int img = blockIdx.x;
    int t = threadIdx.x;
    float sum = 0.f;
    for (int s = t; s < NSEG; s += 64) {
        float4 v = acc[(size_t)s * NIMG + img];
        sum += weight[s + 1] * (fabsf(v.x) * rsqrtf(v.z * v.w));
    }
#pragma unroll
    for (int off = 32; off >= 1; off >>= 1) sum += __shfl_down(sum, off, 64);
    if (t == 0) out[img] = sum + weight[0] + bias[0];
}

extern "C" void kernel_launch(void* const* d_in, const int* in_sizes, int n_in,
                              void* d_out, int out_size, void* d_ws, size_t ws_size,
                              hipStream_t stream) {
    const float* input  = (const float*)d_in[0];
    const float* target = (const float*)d_in[1];
    const int* rows     = (const int*)d_in[2];
    const int* cols     = (const int*)d_in[3];
    const int* segs     = (const int*)d_in[4];
    const float* weight = (const float*)d_in[5];
    const float* bias   = (const float*)d_in[6];
    float* out = (float*)d_out;
    int P = in_sizes[2];

    char* ws = (char*)d_ws;
    float4* acc = (float4*)ws;                               // NSEG*NIMG float4
    size_t accBytes = (size_t)NSEG * NIMG * sizeof(float4);  // 195072 B
    int* seg_start = (int*)(ws + accBytes);                  // 256 ints
    size_t off = accBytes + 256 * sizeof(int);
    off = (off + 255) & ~(size_t)255;
    int2* IDXc = (int2*)(ws + off);                          // P/2 int2 ~2.9 MB
    off += (size_t)(P / 2) * sizeof(int2);
    off = (off + 255) & ~(size_t)255;
    size_t remain = (ws_size > off) ? (ws_size - off) : 0;
    size_t perImg = (size_t)IMGPIX * sizeof(int);            // 1 MB per image
    const int chs[10] = {48, 24, 16, 12, 8, 6, 4, 3, 2, 1};
    int CH = 1;
    for (int i = 0; i < 10; ++i)
        if ((size_t)chs[i] * perImg <= remain) { CH = chs[i]; break; }
    int* G = (int*)(ws + off);

    prep_kernel<<<(P + 255) / 256, 256, 0, stream>>>(rows, cols, segs,
                                                     seg_start, IDXc, P);

    for (int k = 0; k < NIMG; k += CH) {
        dim3 g1(HW / 4, CH);
        fft_rows_kernel<<<g1, 256, 0, stream>>>(input, target, G, k);
        dim3 g2(HW / 4, CH);
        fft_cols_kernel<<<g2, 256, 0, stream>>>(G);
        dim3 g3(CH, NSEG);
        gather_kernel<<<g3, 256, 0, stream>>>(G, IDXc, seg_start, acc, k);
    }
    final_kernel<<<NIMG, 64, 0, stream>>>(acc, weight, bias, out);
}

// Round 14
// 84.301 us; speedup vs baseline: 1.1880x; 1.0061x over previous
//
#include <hip/hip_runtime.h>
#include <hip/hip_fp16.h>

#define HW 512
#define IMGPIX (HW * HW)
#define NSEG 254
#define NIMG 48
#define SLICE 521  // per-slot float2 LDS stride (512 data + skew)

__device__ __forceinline__ int h2_as_int(__half2 h) {
    int r; __builtin_memcpy(&r, &h, 4); return r;
}
__device__ __forceinline__ __half2 int_as_h2(int v) {
    __half2 h; __builtin_memcpy(&h, &v, 4); return h;
}
// Blocked spectrum layout: G[t][ky][j] (ints = half2), t=x>>2, j=x&3.
__device__ __forceinline__ int gidx(int r, int c) {
    return (r >> 2) * 2048 + c * 4 + (r & 3);
}

// ---------------- 8-point DFT in registers (DIF, natural-order outputs) ----
__device__ __forceinline__ void dft8(float xr[8], float xi[8]) {
    const float C = 0.70710678118654752440f;
    float b0r = xr[0] + xr[4], b0i = xi[0] + xi[4];
    float b1r = xr[1] + xr[5], b1i = xi[1] + xi[5];
    float b2r = xr[2] + xr[6], b2i = xi[2] + xi[6];
    float b3r = xr[3] + xr[7], b3i = xi[3] + xi[7];
    float d4r = xr[0] - xr[4], d4i = xi[0] - xi[4];
    float d5r = xr[1] - xr[5], d5i = xi[1] - xi[5];
    float d6r = xr[2] - xr[6], d6i = xi[2] - xi[6];
    float d7r = xr[3] - xr[7], d7i = xi[3] - xi[7];
    float b4r = d4r, b4i = d4i;
    float b5r = C * (d5r + d5i), b5i = C * (d5i - d5r);   // * W8^1
    float b6r = d6i, b6i = -d6r;                          // * -i
    float b7r = C * (d7i - d7r), b7i = -C * (d7r + d7i);  // * W8^3
    float c0r = b0r + b2r, c0i = b0i + b2i;
    float c1r = b1r + b3r, c1i = b1i + b3i;
    float e2r = b0r - b2r, e2i = b0i - b2i;
    float e3r = b1r - b3r, e3i = b1i - b3i;
    float c3r = e3i, c3i = -e3r;                          // * -i
    float c4r = b4r + b6r, c4i = b4i + b6i;
    float c5r = b5r + b7r, c5i = b5i + b7i;
    float e6r = b4r - b6r, e6i = b4i - b6i;
    float e7r = b5r - b7r, e7i = b5i - b7i;
    float c7r = e7i, c7i = -e7r;                          // * -i
    xr[0] = c0r + c1r; xi[0] = c0i + c1i;
    xr[4] = c0r - c1r; xi[4] = c0i - c1i;
    xr[2] = e2r + c3r; xi[2] = e2i + c3i;
    xr[6] = e2r - c3r; xi[6] = e2i - c3i;
    xr[1] = c4r + c5r; xi[1] = c4i + c5i;
    xr[5] = c4r - c5r; xi[5] = c4i - c5i;
    xr[3] = e6r + c7r; xi[3] = e6i + c7i;
    xr[7] = e6r - c7r; xi[7] = e6i - c7i;
}

// Multiply slot k by w^k, w = e^{i*ang}. Native __sinf/__cosf (v_sin_f32 /
// v_cos_f32) — libm sincosf was ~40 VALU ops of range reduction.
__device__ __forceinline__ void tw_apply(float xr[8], float xi[8], float ang) {
    float s = __sinf(ang), c = __cosf(ang);
    float pr = c, pi = s;
#pragma unroll
    for (int k = 1; k < 8; ++k) {
        float tr = xr[k] * pr - xi[k] * pi;
        float ti = xr[k] * pi + xi[k] * pr;
        xr[k] = tr; xi[k] = ti;
        if (k < 7) { float nr = pr * c - pi * s; pi = pr * s + pi * c; pr = nr; }
    }
}

// Per-wave 512-pt FFT. In: slot j holds point n = j*64 + l (natural order).
// Out: lane (hi=l>>3, lo=l&7), slot j3 holds X[hi + 8*lo + 64*j3]; writing
// to ex[hi + (lo<<3) + (j3<<6)] lands X[k] at ex[k]. ex: wave-private
// float2 region. XOR swizzles keep every b64 exchange at the 4-way floor.
// No block barriers; same-wave LDS ordering via s_waitcnt only.
__device__ __forceinline__ void wave_fft512(float xr[8], float xi[8],
                                            float2* ex, int l) {
    const float TWO_PI = 6.28318530717958647692f;
    dft8(xr, xi);
    tw_apply(xr, xi, -TWO_PI * (float)l * (1.0f / 512.0f));
#pragma unroll
    for (int k1 = 0; k1 < 8; ++k1)
        ex[k1 * 64 + (l ^ (k1 << 3))] = make_float2(xr[k1], xi[k1]);
    asm volatile("s_waitcnt lgkmcnt(0)" ::: "memory");
    int hi = l >> 3, lo = l & 7;
#pragma unroll
    for (int m1 = 0; m1 < 8; ++m1) {
        float2 v = ex[hi * 64 + ((m1 ^ hi) << 3) + lo];
        xr[m1] = v.x; xi[m1] = v.y;
    }
    dft8(xr, xi);
    tw_apply(xr, xi, -TWO_PI * (float)lo * (1.0f / 64.0f));
#pragma unroll
    for (int j2 = 0; j2 < 8; ++j2)
        ex[hi * 64 + ((j2 ^ hi) << 3) + (lo ^ hi)] = make_float2(xr[j2], xi[j2]);
    asm volatile("s_waitcnt lgkmcnt(0)" ::: "memory");
#pragma unroll
    for (int m2 = 0; m2 < 8; ++m2) {
        float2 v = ex[hi * 64 + ((lo ^ hi) << 3) + (m2 ^ hi)];
        xr[m2] = v.x; xi[m2] = v.y;
    }
    dft8(xr, xi);
}

// Pass 1: row FFT (re=input, im=target packing). TWO rows per wave: all 32
// input loads issue at kernel start (8KB in flight/wave), so row B's HBM
// latency hides under row A's FFT+restage (T14 issue-early). The two row
// groups (t-group 0: rows 8bx..8bx+3, group 1: 8bx+4..+7) share the same
// 4 LDS slices in two phases -> LDS stays 16.5KB (8 blocks/CU, 32 waves).
__global__ __launch_bounds__(256) void fft_rows_kernel(
    const float* __restrict__ input, const float* __restrict__ target,
    int* __restrict__ G, int img_offset) {
    __shared__ float2 ex[4 * SLICE];
    int tid = threadIdx.x, w = tid >> 6, l = tid & 63;
    int bx = blockIdx.x;
    int li = blockIdx.y;
    size_t base = (size_t)(img_offset + li) * IMGPIX;
    const float* ibA = input + base + (size_t)(8 * bx + w) * HW;
    const float* tbA = target + base + (size_t)(8 * bx + w) * HW;
    const float* ibB = input + base + (size_t)(8 * bx + 4 + w) * HW;
    const float* tbB = target + base + (size_t)(8 * bx + 4 + w) * HW;
    float ar[8], ai[8], br[8], bi[8];
#pragma unroll
    for (int j = 0; j < 8; ++j) {
        ar[j] = ibA[j * 64 + l];
        ai[j] = tbA[j * 64 + l];
        br[j] = ibB[j * 64 + l];
        bi[j] = tbB[j * 64 + l];
    }
    float2* slice = ex + (size_t)w * SLICE;
    int* isl = (int*)slice;
    int* i0 = (int*)ex;
    const int SL2 = SLICE * 2;  // int stride between slices
    int hi = l >> 3, lo = l & 7;

    // ---- phase A: rows 8bx..8bx+3 (t = 2bx) ----
    wave_fft512(ar, ai, slice, l);
#pragma unroll
    for (int j3 = 0; j3 < 8; ++j3)
        isl[hi + (lo << 3) + (j3 << 6)] =
            h2_as_int(__float22half2_rn(make_float2(ar[j3], ai[j3])));
    __syncthreads();
    {
        int* Gt = G + (size_t)li * IMGPIX + (2 * bx) * 2048;
#pragma unroll
        for (int it = 0; it < 2; ++it) {
            int ky = it * 256 + tid;
            int4 o;
            o.x = i0[0 * SL2 + ky];
            o.y = i0[1 * SL2 + ky];
            o.z = i0[2 * SL2 + ky];
            o.w = i0[3 * SL2 + ky];
            *(int4*)(Gt + ky * 4) = o;
        }
    }
    __syncthreads();  // restage reads done before phase B overwrites slices

    // ---- phase B: rows 8bx+4..8bx+7 (t = 2bx+1), same slices ----
    wave_fft512(br, bi, slice, l);
#pragma unroll
    for (int j3 = 0; j3 < 8; ++j3)
        isl[hi + (lo << 3) + (j3 << 6)] =
            h2_as_int(__float22half2_rn(make_float2(br[j3], bi[j3])));
    __syncthreads();
    {
        int* Gt = G + (size_t)li * IMGPIX + (2 * bx + 1) * 2048;
#pragma unroll
        for (int it = 0; it < 2; ++it) {
            int ky = it * 256 + tid;
            int4 o;
            o.x = i0[0 * SL2 + ky];
            o.y = i0[1 * SL2 + ky];
            o.z = i0[2 * SL2 + ky];
            o.w = i0[3 * SL2 + ky];
            *(int4*)(Gt + ky * 4) = o;
        }
    }
}

// Pass 2: x-FFT of 4 ky-columns per block (one per wave, 256 threads),
// in place on the blocked layout. 16.7KB LDS -> 8 blocks/CU.
// DO NOT add gather/map code here: every fused variant (rounds 4-8) made
// hipcc starve this kernel to 32-36 VGPR (needs ~52) -> 3-6x slower.
__global__ __launch_bounds__(256) void fft_cols_kernel(int* __restrict__ G) {
    __shared__ float2 tile[4 * SLICE];
    int tid = threadIdx.x, w = tid >> 6, l = tid & 63;
    int ky0 = blockIdx.x * 4;
    int* Gi = G + (size_t)blockIdx.y * IMGPIX;
#pragma unroll
    for (int it = 0; it < 2; ++it) {
        int m = it * 256 + tid;
        int t = m >> 2, s = m & 3;
        int4 v = *(const int4*)(Gi + t * 2048 + (ky0 + s) * 4);
        float2* dst = tile + s * SLICE + 4 * t;
        dst[0] = __half22float2(int_as_h2(v.x));
        dst[1] = __half22float2(int_as_h2(v.y));
        dst[2] = __half22float2(int_as_h2(v.z));
        dst[3] = __half22float2(int_as_h2(v.w));
    }
    __syncthreads();
    float xr[8], xi[8];
#pragma unroll
    for (int j = 0; j < 8; ++j) {
        float2 v = tile[w * SLICE + j * 64 + l];
        xr[j] = v.x; xi[j] = v.y;
    }
    wave_fft512(xr, xi, tile + w * SLICE, l);  // wave-private slice scratch
    int hi = l >> 3, lo = l & 7;
#pragma unroll
    for (int j3 = 0; j3 < 8; ++j3)
        tile[w * SLICE + hi + (lo << 3) + (j3 << 6)] = make_float2(xr[j3], xi[j3]);
    __syncthreads();
#pragma unroll
    for (int it = 0; it < 2; ++it) {
        int m = it * 256 + tid;
        int t = m >> 2, s = m & 3;
        const float2* src = tile + s * SLICE + 4 * t;
        int4 o;
        o.x = h2_as_int(__float22half2_rn(src[0]));
        o.y = h2_as_int(__float22half2_rn(src[1]));
        o.z = h2_as_int(__float22half2_rn(src[2]));
        o.w = h2_as_int(__float22half2_rn(src[3]));
        *(int4*)(Gi + t * 2048 + (ky0 + s) * 4) = o;
    }
}

// Prep: segment boundaries + compacted CANONICAL pair-index list. Bresenham
// emits 8 octant entries per step; the central mirror of group position j
// in {0,1,4,5} is {3,2,7,6}[j] — canonical q -> list position
// p = 8*(q>>2) + LUT[q&3], no data-dependent branch. Mirror entries give
// the exact conjugate (same Re-cross/e1/e2): the 1/2 cancels in FRC.
__global__ void prep_kernel(const int* __restrict__ rows,
                            const int* __restrict__ cols,
                            const int* __restrict__ segs,
                            int* __restrict__ seg_start,
                            int2* __restrict__ IDXc, int P) {
    int p = blockIdx.x * 256 + threadIdx.x;
    if (p >= P) return;
    if (p == 0) {
        seg_start[0] = 0;
        seg_start[NSEG] = P;
    } else if (segs[p] != segs[p - 1]) {
        seg_start[segs[p]] = p;
    }
    int q = p;  // reuse thread index as canonical index for q < P/2
    if (q < (P >> 1)) {
        const int LUT[4] = {0, 1, 4, 5};
        int src = ((q >> 2) << 3) + LUT[q & 3];
        int r = rows[src], c = cols[src];
        IDXc[q] = make_int2(gidx(r, c), gidx(HW - r, HW - c));
    }
}

// One 256-thread block (4 waves) per (local img, segment), canonical half
// only. STRAIGHT-LINE body — a data-dependent `continue` kills the
// compiler's load pipelining (round 11: VGPR 12, 3.4x slower).
__global__ __launch_bounds__(256) void gather_kernel(
    const int* __restrict__ G, const int2* __restrict__ IDXc,
    const int* __restrict__ seg_start, float4* __restrict__ acc,
    int img_offset) {
    int li = blockIdx.x;
    int s = blockIdx.y;
    int q0 = seg_start[s] >> 1, q1 = seg_start[s + 1] >> 1;
    const int* A = G + (size_t)li * IMGPIX;
    float cr = 0.f, e1 = 0.f, e2 = 0.f;
    for (int q = q0 + threadIdx.x; q < q1; q += 256) {
        int2 ix = IDXc[q];
        float2 u = __half22float2(int_as_h2(A[ix.x]));
        float2 v = __half22float2(int_as_h2(A[ix.y]));
        float ar = u.x + v.x, ai = u.y - v.y;
        float br = u.y + v.y, bi = v.x - u.x;
        cr += ar * br + ai * bi;
        e1 += ar * ar + ai * ai;
        e2 += br * br + bi * bi;
    }
#pragma unroll
    for (int off = 32; off >= 1; off >>= 1) {
        cr += __shfl_down(cr, off, 64);
        e1 += __shfl_down(e1, off, 64);
        e2 += __shfl_down(e2, off, 64);
    }
    __shared__ float4 part[4];
    int wid = threadIdx.x >> 6, lane = threadIdx.x & 63;
    if (lane == 0) part[wid] = make_float4(cr, 0.f, e1, e2);
    __syncthreads();
    if (threadIdx.x == 0) {
        float4 t0 = part[0], t1 = part[1], t2 = part[2], t3 = part[3];
        acc[(size_t)s * NIMG + (img_offset + li)] =
            make_float4(t0.x + t1.x + t2.x + t3.x, 0.f,
                        t0.z + t1.z + t2.z + t3.z, t0.w + t1.w + t2.w + t3.w);
    }
}

__global__ __launch_bounds__(64) void final_kernel(
    const float4* __restrict__ acc, const float* __restrict__ weight,
    const float* __restrict__ bias, float* __restrict__ out) {
    int img = blockIdx.x;
    int t = threadIdx.x;
    float sum = 0.f;
    for (int s = t; s < NSEG; s += 64) {
        float4 v = acc[(size_t)s * NIMG + img];
        sum += weight[s + 1] * (fabsf(v.x) * rsqrtf(v.z * v.w));
    }
#pragma unroll
    for (int off = 32; off >= 1; off >>= 1) sum += __shfl_down(sum, off, 64);
    if (t == 0) out[img] = sum + weight[0] + bias[0];
}

extern "C" void kernel_launch(void* const* d_in, const int* in_sizes, int n_in,
                              void* d_out, int out_size, void* d_ws, size_t ws_size,
                              hipStream_t stream) {
    const float* input  = (const float*)d_in[0];
    const float* target = (const float*)d_in[1];
    const int* rows     = (const int*)d_in[2];
    const int* cols     = (const int*)d_in[3];
    const int* segs     = (const int*)d_in[4];
    const float* weight = (const float*)d_in[5];
    const float* bias   = (const float*)d_in[6];
    float* out = (float*)d_out;
    int P = in_sizes[2];

    char* ws = (char*)d_ws;
    float4* acc = (float4*)ws;                               // NSEG*NIMG float4
    size_t accBytes = (size_t)NSEG * NIMG * sizeof(float4);  // 195072 B
    int* seg_start = (int*)(ws + accBytes);                  // 256 ints
    size_t off = accBytes + 256 * sizeof(int);
    off = (off + 255) & ~(size_t)255;
    int2* IDXc = (int2*)(ws + off);                          // P/2 int2 ~2.9 MB
    off += (size_t)(P / 2) * sizeof(int2);
    off = (off + 255) & ~(size_t)255;
    size_t remain = (ws_size > off) ? (ws_size - off) : 0;
    size_t perImg = (size_t)IMGPIX * sizeof(int);            // 1 MB per image
    const int chs[10] = {48, 24, 16, 12, 8, 6, 4, 3, 2, 1};
    int CH = 1;
    for (int i = 0; i < 10; ++i)
        if ((size_t)chs[i] * perImg <= remain) { CH = chs[i]; break; }
    int* G = (int*)(ws + off);

    prep_kernel<<<(P + 255) / 256, 256, 0, stream>>>(rows, cols, segs,
                                                     seg_start, IDXc, P);

    for (int k = 0; k < NIMG; k += CH) {
        dim3 g1(HW / 8, CH);
        fft_rows_kernel<<<g1, 256, 0, stream>>>(input, target, G, k);
        dim3 g2(HW / 4, CH);
        fft_cols_kernel<<<g2, 256, 0, stream>>>(G);
        dim3 g3(CH, NSEG);
        gather_kernel<<<g3, 256, 0, stream>>>(G, IDXc, seg_start, acc, k);
    }
    final_kernel<<<NIMG, 64, 0, stream>>>(acc, weight, bias, out);
}

// Round 15
// 84.250 us; speedup vs baseline: 1.1887x; 1.0006x over previous
//
#include <hip/hip_runtime.h>
#include <hip/hip_fp16.h>

#define HW 512
#define IMGPIX (HW * HW)
#define NSEG 254
#define NIMG 48
#define SLICE 521  // per-slot float2 LDS stride (512 data + skew)

__device__ __forceinline__ int h2_as_int(__half2 h) {
    int r; __builtin_memcpy(&r, &h, 4); return r;
}
__device__ __forceinline__ __half2 int_as_h2(int v) {
    __half2 h; __builtin_memcpy(&h, &v, 4); return h;
}
// Blocked spectrum layout: G[t][ky][j] (ints = half2), t=x>>2, j=x&3.
__device__ __forceinline__ int gidx(int r, int c) {
    return (r >> 2) * 2048 + c * 4 + (r & 3);
}

// ---------------- 8-point DFT in registers (DIF, natural-order outputs) ----
__device__ __forceinline__ void dft8(float xr[8], float xi[8]) {
    const float C = 0.70710678118654752440f;
    float b0r = xr[0] + xr[4], b0i = xi[0] + xi[4];
    float b1r = xr[1] + xr[5], b1i = xi[1] + xi[5];
    float b2r = xr[2] + xr[6], b2i = xi[2] + xi[6];
    float b3r = xr[3] + xr[7], b3i = xi[3] + xi[7];
    float d4r = xr[0] - xr[4], d4i = xi[0] - xi[4];
    float d5r = xr[1] - xr[5], d5i = xi[1] - xi[5];
    float d6r = xr[2] - xr[6], d6i = xi[2] - xi[6];
    float d7r = xr[3] - xr[7], d7i = xi[3] - xi[7];
    float b4r = d4r, b4i = d4i;
    float b5r = C * (d5r + d5i), b5i = C * (d5i - d5r);   // * W8^1
    float b6r = d6i, b6i = -d6r;                          // * -i
    float b7r = C * (d7i - d7r), b7i = -C * (d7r + d7i);  // * W8^3
    float c0r = b0r + b2r, c0i = b0i + b2i;
    float c1r = b1r + b3r, c1i = b1i + b3i;
    float e2r = b0r - b2r, e2i = b0i - b2i;
    float e3r = b1r - b3r, e3i = b1i - b3i;
    float c3r = e3i, c3i = -e3r;                          // * -i
    float c4r = b4r + b6r, c4i = b4i + b6i;
    float c5r = b5r + b7r, c5i = b5i + b7i;
    float e6r = b4r - b6r, e6i = b4i - b6i;
    float e7r = b5r - b7r, e7i = b5i - b7i;
    float c7r = e7i, c7i = -e7r;                          // * -i
    xr[0] = c0r + c1r; xi[0] = c0i + c1i;
    xr[4] = c0r - c1r; xi[4] = c0i - c1i;
    xr[2] = e2r + c3r; xi[2] = e2i + c3i;
    xr[6] = e2r - c3r; xi[6] = e2i - c3i;
    xr[1] = c4r + c5r; xi[1] = c4i + c5i;
    xr[5] = c4r - c5r; xi[5] = c4i - c5i;
    xr[3] = e6r + c7r; xi[3] = e6i + c7i;
    xr[7] = e6r - c7r; xi[7] = e6i - c7i;
}

// Multiply slot k by w^k, w = e^{i*ang}. Each power computed INDEPENDENTLY
// via native __sinf/__cosf(k*ang): 7 parallel trans pairs + 7 parallel
// complex muls — no serial twiddle chain (the round-13 chain was ~56
// dependent cycles per call, x3 per FFT, on a dependency-stalled kernel).
__device__ __forceinline__ void tw_apply(float xr[8], float xi[8], float ang) {
#pragma unroll
    for (int k = 1; k < 8; ++k) {
        float s = __sinf((float)k * ang), c = __cosf((float)k * ang);
        float tr = xr[k] * c - xi[k] * s;
        float ti = xr[k] * s + xi[k] * c;
        xr[k] = tr; xi[k] = ti;
    }
}

// Per-wave 512-pt FFT. In: slot j holds point n = j*64 + l (natural order).
// Out: lane (hi=l>>3, lo=l&7), slot j3 holds X[hi + 8*lo + 64*j3]; writing
// to ex[hi + (lo<<3) + (j3<<6)] lands X[k] at ex[k]. ex: wave-private
// float2 region. XOR swizzles keep every b64 exchange at the 4-way floor.
// No block barriers; same-wave LDS ordering via s_waitcnt only.
__device__ __forceinline__ void wave_fft512(float xr[8], float xi[8],
                                            float2* ex, int l) {
    const float TWO_PI = 6.28318530717958647692f;
    dft8(xr, xi);
    tw_apply(xr, xi, -TWO_PI * (float)l * (1.0f / 512.0f));
#pragma unroll
    for (int k1 = 0; k1 < 8; ++k1)
        ex[k1 * 64 + (l ^ (k1 << 3))] = make_float2(xr[k1], xi[k1]);
    asm volatile("s_waitcnt lgkmcnt(0)" ::: "memory");
    int hi = l >> 3, lo = l & 7;
#pragma unroll
    for (int m1 = 0; m1 < 8; ++m1) {
        float2 v = ex[hi * 64 + ((m1 ^ hi) << 3) + lo];
        xr[m1] = v.x; xi[m1] = v.y;
    }
    dft8(xr, xi);
    tw_apply(xr, xi, -TWO_PI * (float)lo * (1.0f / 64.0f));
#pragma unroll
    for (int j2 = 0; j2 < 8; ++j2)
        ex[hi * 64 + ((j2 ^ hi) << 3) + (lo ^ hi)] = make_float2(xr[j2], xi[j2]);
    asm volatile("s_waitcnt lgkmcnt(0)" ::: "memory");
#pragma unroll
    for (int m2 = 0; m2 < 8; ++m2) {
        float2 v = ex[hi * 64 + ((lo ^ hi) << 3) + (m2 ^ hi)];
        xr[m2] = v.x; xi[m2] = v.y;
    }
    dft8(xr, xi);
}

// Pass 1: row FFT (re=input, im=target packing), ONE row per wave, 4 waves
// per block, 6144 blocks (round-13 proven config — the 2-rows-per-wave
// variant of round 14 halved the grid, tripled the barriers, and dropped
// occupancy 55->29%: reverted). Results converted to fp16, emitted in the
// BLOCKED layout G[t][ky][j] via LDS restage (512 contiguous int4 stores).
__global__ __launch_bounds__(256) void fft_rows_kernel(
    const float* __restrict__ input, const float* __restrict__ target,
    int* __restrict__ G, int img_offset) {
    __shared__ float2 ex[4 * SLICE];
    int tid = threadIdx.x, w = tid >> 6, l = tid & 63;
    int t = blockIdx.x;
    int x = t * 4 + w;
    int li = blockIdx.y;
    const float* ib = input + (size_t)(img_offset + li) * IMGPIX + (size_t)x * HW;
    const float* tb = target + (size_t)(img_offset + li) * IMGPIX + (size_t)x * HW;
    float xr[8], xi[8];
#pragma unroll
    for (int j = 0; j < 8; ++j) {
        xr[j] = ib[j * 64 + l];
        xi[j] = tb[j * 64 + l];
    }
    wave_fft512(xr, xi, ex + w * SLICE, l);
    // fp16 into wave-private int slice (aliases this wave's dead scratch).
    int* isl = (int*)(ex + (size_t)w * SLICE);
    int hi = l >> 3, lo = l & 7;
#pragma unroll
    for (int j3 = 0; j3 < 8; ++j3)
        isl[hi + (lo << 3) + (j3 << 6)] =
            h2_as_int(__float22half2_rn(make_float2(xr[j3], xi[j3])));
    __syncthreads();
    int* i0 = (int*)ex;
    const int SL2 = SLICE * 2;  // int stride between slices
    int* Gt = G + (size_t)li * IMGPIX + t * 2048;
#pragma unroll
    for (int it = 0; it < 2; ++it) {
        int ky = it * 256 + tid;
        int4 o;
        o.x = i0[0 * SL2 + ky];
        o.y = i0[1 * SL2 + ky];
        o.z = i0[2 * SL2 + ky];
        o.w = i0[3 * SL2 + ky];
        *(int4*)(Gt + ky * 4) = o;
    }
}

// Pass 2: x-FFT of 4 ky-columns per block (one per wave, 256 threads),
// in place on the blocked layout. 16.7KB LDS -> 8 blocks/CU.
// DO NOT add gather/map code here: every fused variant (rounds 4-8) made
// hipcc starve this kernel to 32-36 VGPR (needs ~52) -> 3-6x slower.
__global__ __launch_bounds__(256) void fft_cols_kernel(int* __restrict__ G) {
    __shared__ float2 tile[4 * SLICE];
    int tid = threadIdx.x, w = tid >> 6, l = tid & 63;
    int ky0 = blockIdx.x * 4;
    int* Gi = G + (size_t)blockIdx.y * IMGPIX;
#pragma unroll
    for (int it = 0; it < 2; ++it) {
        int m = it * 256 + tid;
        int t = m >> 2, s = m & 3;
        int4 v = *(const int4*)(Gi + t * 2048 + (ky0 + s) * 4);
        float2* dst = tile + s * SLICE + 4 * t;
        dst[0] = __half22float2(int_as_h2(v.x));
        dst[1] = __half22float2(int_as_h2(v.y));
        dst[2] = __half22float2(int_as_h2(v.z));
        dst[3] = __half22float2(int_as_h2(v.w));
    }
    __syncthreads();
    float xr[8], xi[8];
#pragma unroll
    for (int j = 0; j < 8; ++j) {
        float2 v = tile[w * SLICE + j * 64 + l];
        xr[j] = v.x; xi[j] = v.y;
    }
    wave_fft512(xr, xi, tile + w * SLICE, l);  // wave-private slice scratch
    int hi = l >> 3, lo = l & 7;
#pragma unroll
    for (int j3 = 0; j3 < 8; ++j3)
        tile[w * SLICE + hi + (lo << 3) + (j3 << 6)] = make_float2(xr[j3], xi[j3]);
    __syncthreads();
#pragma unroll
    for (int it = 0; it < 2; ++it) {
        int m = it * 256 + tid;
        int t = m >> 2, s = m & 3;
        const float2* src = tile + s * SLICE + 4 * t;
        int4 o;
        o.x = h2_as_int(__float22half2_rn(src[0]));
        o.y = h2_as_int(__float22half2_rn(src[1]));
        o.z = h2_as_int(__float22half2_rn(src[2]));
        o.w = h2_as_int(__float22half2_rn(src[3]));
        *(int4*)(Gi + t * 2048 + (ky0 + s) * 4) = o;
    }
}

// Prep: segment boundaries + compacted CANONICAL pair-index list. Bresenham
// emits 8 octant entries per step; the central mirror of group position j
// in {0,1,4,5} is {3,2,7,6}[j] — canonical q -> list position
// p = 8*(q>>2) + LUT[q&3], no data-dependent branch. Mirror entries give
// the exact conjugate (same Re-cross/e1/e2): the 1/2 cancels in FRC.
__global__ void prep_kernel(const int* __restrict__ rows,
                            const int* __restrict__ cols,
                            const int* __restrict__ segs,
                            int* __restrict__ seg_start,
                            int2* __restrict__ IDXc, int P) {
    int p = blockIdx.x * 256 + threadIdx.x;
    if (p >= P) return;
    if (p == 0) {
        seg_start[0] = 0;
        seg_start[NSEG] = P;
    } else if (segs[p] != segs[p - 1]) {
        seg_start[segs[p]] = p;
    }
    int q = p;  // reuse thread index as canonical index for q < P/2
    if (q < (P >> 1)) {
        const int LUT[4] = {0, 1, 4, 5};
        int src = ((q >> 2) << 3) + LUT[q & 3];
        int r = rows[src], c = cols[src];
        IDXc[q] = make_int2(gidx(r, c), gidx(HW - r, HW - c));
    }
}

// One 256-thread block (4 waves) per (local img, segment), canonical half
// only. STRAIGHT-LINE body — a data-dependent `continue` kills the
// compiler's load pipelining (round 11: VGPR 12, 3.4x slower).
__global__ __launch_bounds__(256) void gather_kernel(
    const int* __restrict__ G, const int2* __restrict__ IDXc,
    const int* __restrict__ seg_start, float4* __restrict__ acc,
    int img_offset) {
    int li = blockIdx.x;
    int s = blockIdx.y;
    int q0 = seg_start[s] >> 1, q1 = seg_start[s + 1] >> 1;
    const int* A = G + (size_t)li * IMGPIX;
    float cr = 0.f, e1 = 0.f, e2 = 0.f;
    for (int q = q0 + threadIdx.x; q < q1; q += 256) {
        int2 ix = IDXc[q];
        float2 u = __half22float2(int_as_h2(A[ix.x]));
        float2 v = __half22float2(int_as_h2(A[ix.y]));
        float ar = u.x + v.x, ai = u.y - v.y;
        float br = u.y + v.y, bi = v.x - u.x;
        cr += ar * br + ai * bi;
        e1 += ar * ar + ai * ai;
        e2 += br * br + bi * bi;
    }
#pragma unroll
    for (int off = 32; off >= 1; off >>= 1) {
        cr += __shfl_down(cr, off, 64);
        e1 += __shfl_down(e1, off, 64);
        e2 += __shfl_down(e2, off, 64);
    }
    __shared__ float4 part[4];
    int wid = threadIdx.x >> 6, lane = threadIdx.x & 63;
    if (lane == 0) part[wid] = make_float4(cr, 0.f, e1, e2);
    __syncthreads();
    if (threadIdx.x == 0) {
        float4 t0 = part[0], t1 = part[1], t2 = part[2], t3 = part[3];
        acc[(size_t)s * NIMG + (img_offset + li)] =
            make_float4(t0.x + t1.x + t2.x + t3.x, 0.f,
                        t0.z + t1.z + t2.z + t3.z, t0.w + t1.w + t2.w + t3.w);
    }
}

__global__ __launch_bounds__(64) void final_kernel(
    const float4* __restrict__ acc, const float* __restrict__ weight,
    const float* __restrict__ bias, float* __restrict__ out) {
    int img = blockIdx.x;
    int t = threadIdx.x;
    float sum = 0.f;
    for (int s = t; s < NSEG; s += 64) {
        float4 v = acc[(size_t)s * NIMG + img];
        sum += weight[s + 1] * (fabsf(v.x) * rsqrtf(v.z * v.w));
    }
#pragma unroll
    for (int off = 32; off >= 1; off >>= 1) sum += __shfl_down(sum, off, 64);
    if (t == 0) out[img] = sum + weight[0] + bias[0];
}

extern "C" void kernel_launch(void* const* d_in, const int* in_sizes, int n_in,
                              void* d_out, int out_size, void* d_ws, size_t ws_size,
                              hipStream_t stream) {
    const float* input  = (const float*)d_in[0];
    const float* target = (const float*)d_in[1];
    const int* rows     = (const int*)d_in[2];
    const int* cols     = (const int*)d_in[3];
    const int* segs     = (const int*)d_in[4];
    const float* weight = (const float*)d_in[5];
    const float* bias   = (const float*)d_in[6];
    float* out = (float*)d_out;
    int P = in_sizes[2];

    char* ws = (char*)d_ws;
    float4* acc = (float4*)ws;                               // NSEG*NIMG float4
    size_t accBytes = (size_t)NSEG * NIMG * sizeof(float4);  // 195072 B
    int* seg_start = (int*)(ws + accBytes);                  // 256 ints
    size_t off = accBytes + 256 * sizeof(int);
    off = (off + 255) & ~(size_t)255;
    int2* IDXc = (int2*)(ws + off);                          // P/2 int2 ~0.73 MB
    off += (size_t)(P / 2) * sizeof(int2);
    off = (off + 255) & ~(size_t)255;
    size_t remain = (ws_size > off) ? (ws_size - off) : 0;
    size_t perImg = (size_t)IMGPIX * sizeof(int);            // 1 MB per image
    const int chs[10] = {48, 24, 16, 12, 8, 6, 4, 3, 2, 1};
    int CH = 1;
    for (int i = 0; i < 10; ++i)
        if ((size_t)chs[i] * perImg <= remain) { CH = chs[i]; break; }
    int* G = (int*)(ws + off);

    prep_kernel<<<(P + 255) / 256, 256, 0, stream>>>(rows, cols, segs,
                                                     seg_start, IDXc, P);

    for (int k = 0; k < NIMG; k += CH) {
        dim3 g1(HW / 4, CH);
        fft_rows_kernel<<<g1, 256, 0, stream>>>(input, target, G, k);
        dim3 g2(HW / 4, CH);
        fft_cols_kernel<<<g2, 256, 0, stream>>>(G);
        dim3 g3(CH, NSEG);
        gather_kernel<<<g3, 256, 0, stream>>>(G, IDXc, seg_start, acc, k);
    }
    final_kernel<<<NIMG, 64, 0, stream>>>(acc, weight, bias, out);
}